// Round 4
// baseline (186.316 us; speedup 1.0000x reference)
//
#include <hip/hip_runtime.h>
#include <stdint.h>

// Problem constants (from setup_inputs: N=50000, T=401 -> 400 SDE steps, M=64)
#define N_PART  50000
#define HALF_N  25000
#define STEPS   400
#define T_PTS   401
#define CHUNKS  20
#define SPC     (STEPS / CHUNKS)     // 20 steps per chunk
#define BITS_SPLIT 75000u            // threefry counter split: 150000 bits -> two halves
#define NSPLIT  8

// ---------------- Threefry-2x32 (exact JAX semantics, 20 rounds) ----------------
__device__ __forceinline__ void threefry2x32(uint32_t k0, uint32_t k1,
                                             uint32_t x0, uint32_t x1,
                                             uint32_t& o0, uint32_t& o1) {
  const uint32_t ks2 = k0 ^ k1 ^ 0x1BD11BDAu;
  x0 += k0; x1 += k1;
#define RND(r) { x0 += x1; x1 = (x1 << r) | (x1 >> (32 - r)); x1 ^= x0; }
  RND(13) RND(15) RND(26) RND(6)
  x0 += k1;  x1 += ks2 + 1u;
  RND(17) RND(29) RND(16) RND(24)
  x0 += ks2; x1 += k0 + 2u;
  RND(13) RND(15) RND(26) RND(6)
  x0 += k0;  x1 += k1 + 3u;
  RND(17) RND(29) RND(16) RND(24)
  x0 += k1;  x1 += ks2 + 4u;
  RND(13) RND(15) RND(26) RND(6)
  x0 += ks2; x1 += k0 + 5u;
#undef RND
  o0 = x0; o1 = x1;
}

// bits -> erfinv(u) for u ~ U(-1,1) exactly as jax.random.normal modulo <=1e-6 diffs:
//  - u = 2m-3 (m in [1,2)) fused, clamped at nextafter(-1,0)  [clamp REQUIRED: m==1 -> log(0)]
//  - t = fma(-u,u,1): single-rounded 1-u^2, no cancellation
//  - w = -ln2*log2(t) via hardware v_log_f32; branch on L directly
// sqrt(2) is folded into the weight table.
__device__ __forceinline__ float bits_to_erfinv(uint32_t bits) {
  const float lo = __uint_as_float(0xBF7FFFFFu);                 // -(1-2^-24)
  float m = __uint_as_float((bits >> 9) | 0x3F800000u);          // [1,2)
  float u = fmaxf(lo, fmaf(m, 2.0f, -3.0f));                    // (-1,1)
  float t = fmaf(-u, u, 1.0f);
  float L = __log2f(t);                                          // v_log_f32, L <= 0
  float p;
  if (L > -7.2134752f) {                                         // w = -ln2*L < 5
    float w = fmaf(L, -0.69314718056f, -2.5f);
    p = 2.81022636e-08f;
    p = fmaf(p, w, 3.43273939e-07f);
    p = fmaf(p, w, -3.5233877e-06f);
    p = fmaf(p, w, -4.39150654e-06f);
    p = fmaf(p, w, 0.00021858087f);
    p = fmaf(p, w, -0.00125372503f);
    p = fmaf(p, w, -0.00417768164f);
    p = fmaf(p, w, 0.246640727f);
    p = fmaf(p, w, 1.50140941f);
  } else {
    float w = sqrtf(L * -0.69314718056f) - 3.0f;
    p = -0.000200214257f;
    p = fmaf(p, w, 0.000100950558f);
    p = fmaf(p, w, 0.00134934322f);
    p = fmaf(p, w, -0.00367342844f);
    p = fmaf(p, w, 0.00573950773f);
    p = fmaf(p, w, -0.0076224613f);
    p = fmaf(p, w, 0.00943887047f);
    p = fmaf(p, w, 1.00167406f);
    p = fmaf(p, w, 2.83297682f);
  }
  return p * u;
}

// ---------------- Kernel 0: env->suffix W (x sqrt2) + keys, zero accums ----------------
__global__ __launch_bounds__(512) void setup_kernel(
    const int* __restrict__ delta_us, const int* __restrict__ Delta_us,
    const int* __restrict__ dt_us, const int* __restrict__ seed,
    uint4* __restrict__ kw, float* __restrict__ Sbuf, float* __restrict__ acc) {
  __shared__ float env_s[T_PTS];
  int tid = threadIdx.x;

  if (blockIdx.x == 0) {
    if (tid < T_PTS) {
      float u  = (float)dt_us[0]    * 1e-6f;   // rise = dt
      float df = (float)delta_us[0] * 1e-6f;
      float Df = (float)Delta_us[0] * 1e-6f;
      float tm = (float)tid * u;
      float c1 = fminf(fmaxf(tm / u, 0.0f), 1.0f);
      float c2 = fminf(fmaxf((tm - df) / u, 0.0f), 1.0f);
      float c3 = fminf(fmaxf((tm - Df) / u, 0.0f), 1.0f);
      float c4 = fminf(fmaxf(((tm - Df) - df) / u, 0.0f), 1.0f);
      env_s[tid] = (c1 - c2) - (c3 - c4);
    }
    __syncthreads();
    if (tid < STEPS) {
      float w = 0.0f;
      for (int t = tid + 1; t < T_PTS; ++t) w += env_s[t];
      uint32_t o0, o1;  // fold_in(key(seed), i) = threefry((0,seed),(0,i))
      threefry2x32(0u, (uint32_t)seed[0], 0u, (uint32_t)tid, o0, o1);
      kw[tid] = make_uint4(o0, o1, __float_as_uint(1.41421356237309515f * w), 0u);
    }
  }
  // zero S buffer; zero 128 partial sums + completion counter
  for (int i = blockIdx.x * blockDim.x + tid; i < N_PART * 3; i += gridDim.x * blockDim.x)
    Sbuf[i] = 0.0f;
  if (blockIdx.x == 1 && tid < 132) acc[tid] = 0.0f;
}

// ---------------- Kernel 1: per particle-pair weighted noise accumulation ----------------
__global__ __launch_bounds__(256) void sde_kernel(const uint4* __restrict__ kw,
                                                  const float* __restrict__ D_long,
                                                  const float* __restrict__ D_trans,
                                                  const int* __restrict__ dt_us,
                                                  float* __restrict__ Sbuf) {
  uint32_t tid = blockIdx.x * 256 + threadIdx.x;
  uint32_t chunk = tid / HALF_N;           // 20 chunks x 25000 pairs
  uint32_t p = tid - chunk * HALF_N;
  if (chunk >= CHUNKS) return;
  const uint32_t c0 = 3u * p;
  const int i0 = (int)chunk * SPC;

  float a0x = 0.f, a0y = 0.f, a0z = 0.f;   // particle p
  float a1x = 0.f, a1y = 0.f, a1z = 0.f;   // particle p + 25000

  for (int s = 0; s < SPC; ++s) {
    uint4 k = kw[i0 + s];
    float w = __uint_as_float(k.z);        // sqrt(2) * suffix-weight
    uint32_t o0, o1;
    threefry2x32(k.x, k.y, c0,      c0 + BITS_SPLIT,      o0, o1);
    a0x = fmaf(w, bits_to_erfinv(o0), a0x);
    a1x = fmaf(w, bits_to_erfinv(o1), a1x);
    threefry2x32(k.x, k.y, c0 + 1u, c0 + 1u + BITS_SPLIT, o0, o1);
    a0y = fmaf(w, bits_to_erfinv(o0), a0y);
    a1y = fmaf(w, bits_to_erfinv(o1), a1y);
    threefry2x32(k.x, k.y, c0 + 2u, c0 + 2u + BITS_SPLIT, o0, o1);
    a0z = fmaf(w, bits_to_erfinv(o0), a0z);
    a1z = fmaf(w, bits_to_erfinv(o1), a1z);
  }

  float twodt = 2.0f * ((float)dt_us[0] * 1e-6f);
  float st = sqrtf(twodt * D_trans[0]);
  float sl = sqrtf(twodt * D_long[0]);

  atomicAdd(&Sbuf[3 * p + 0], a0x * st);
  atomicAdd(&Sbuf[3 * p + 1], a0y * st);
  atomicAdd(&Sbuf[3 * p + 2], a0z * sl);
  atomicAdd(&Sbuf[3 * (p + HALF_N) + 0], a1x * st);
  atomicAdd(&Sbuf[3 * (p + HALF_N) + 1], a1y * st);
  atomicAdd(&Sbuf[3 * (p + HALF_N) + 2], a1z * sl);
}

// ---------------- Kernel 2: partial cos/sin sums; last block finalizes ----------------
__global__ __launch_bounds__(256) void signal_partial(const float* __restrict__ Sbuf,
                                                      const float* __restrict__ G_amps,
                                                      const float* __restrict__ grad,
                                                      const int* __restrict__ dt_us,
                                                      float* __restrict__ acc,
                                                      float* __restrict__ out) {
  int m = blockIdx.x;
  int n0 = blockIdx.y * (N_PART / NSPLIT);
  int tid = threadIdx.x;
  float Kf = 267.513e6f * ((float)dt_us[0] * 1e-6f);
  float Km = Kf * G_amps[m];
  float gx = grad[3 * m + 0], gy = grad[3 * m + 1], gz = grad[3 * m + 2];

  float cs = 0.f, ss = 0.f;
  for (int n = n0 + tid; n < n0 + N_PART / NSPLIT; n += 256) {
    float sx = Sbuf[3 * n + 0], sy = Sbuf[3 * n + 1], sz = Sbuf[3 * n + 2];
    float ph = Km * (gx * sx + gy * sy + gz * sz);
    float s, c;
    __sincosf(ph, &s, &c);                 // v_sin_f32 / v_cos_f32
    cs += c; ss += s;
  }
  for (int off = 32; off > 0; off >>= 1) {
    cs += __shfl_down(cs, off);
    ss += __shfl_down(ss, off);
  }
  __shared__ float redc[4], reds[4];
  __shared__ int slast;
  int lane = tid & 63, wv = tid >> 6;
  if (lane == 0) { redc[wv] = cs; reds[wv] = ss; }
  __syncthreads();
  if (tid == 0) {
    atomicAdd(&acc[m],      redc[0] + redc[1] + redc[2] + redc[3]);
    atomicAdd(&acc[64 + m], reds[0] + reds[1] + reds[2] + reds[3]);
    __threadfence();
    unsigned* ctr = (unsigned*)&acc[128];
    unsigned done = __hip_atomic_fetch_add(ctr, 1u, __ATOMIC_ACQ_REL, __HIP_MEMORY_SCOPE_AGENT);
    slast = (done == (unsigned)(gridDim.x * gridDim.y) - 1u) ? 1 : 0;
  }
  __syncthreads();
  if (slast && tid < (int)gridDim.x) {
    float c = __hip_atomic_load(&acc[tid],      __ATOMIC_RELAXED, __HIP_MEMORY_SCOPE_AGENT) / (float)N_PART;
    float s = __hip_atomic_load(&acc[64 + tid], __ATOMIC_RELAXED, __HIP_MEMORY_SCOPE_AGENT) / (float)N_PART;
    out[tid] = sqrtf(c * c + s * s);
  }
}

extern "C" void kernel_launch(void* const* d_in, const int* in_sizes, int n_in,
                              void* d_out, int out_size, void* d_ws, size_t ws_size,
                              hipStream_t stream) {
  const float* G_amps   = (const float*)d_in[0];
  const float* grad     = (const float*)d_in[1];
  const float* D_long   = (const float*)d_in[2];
  const float* D_trans  = (const float*)d_in[3];
  const int*   delta_us = (const int*)d_in[4];
  const int*   Delta_us = (const int*)d_in[5];
  const int*   dt_us    = (const int*)d_in[6];
  const int*   seed     = (const int*)d_in[8];

  // ws layout: kw[400] uint4 (6400B) | S[150000] f32 (600000B) | acc[132] f32
  uint4* kw   = (uint4*)d_ws;
  float* Sbuf = (float*)((char*)d_ws + 6400);
  float* acc  = (float*)((char*)d_ws + 6400 + 600000);

  setup_kernel<<<294, 512, 0, stream>>>(delta_us, Delta_us, dt_us, seed, kw, Sbuf, acc);
  int sde_blocks = (CHUNKS * HALF_N + 255) / 256;
  sde_kernel<<<sde_blocks, 256, 0, stream>>>(kw, D_long, D_trans, dt_us, Sbuf);
  int M = in_sizes[0];
  signal_partial<<<dim3(M, NSPLIT), 256, 0, stream>>>(Sbuf, G_amps, grad, dt_us, acc, (float*)d_out);
}